// Round 8
// baseline (121.829 us; speedup 1.0000x reference)
//
#include <hip/hip_runtime.h>
#include <hip/hip_bf16.h>
#include <cmath>

typedef __attribute__((ext_vector_type(4))) float f32x4;
typedef __attribute__((ext_vector_type(8))) short s16x8;
typedef __attribute__((ext_vector_type(4))) short s16x4;
typedef __attribute__((ext_vector_type(4))) unsigned short u16x4;

static constexpr int NCOL = 512;    // L
static constexpr int NBATCH = 1024; // 32*32
static constexpr int SLOT = 64 * NCOL;

__device__ inline unsigned short bf16h(float f) {
  return __builtin_bit_cast(unsigned short, __float2bfloat16(f));
}
__device__ inline float bf16f(unsigned short h) {
  unsigned u = ((unsigned)h) << 16;
  return __builtin_bit_cast(float, u);
}

// 8B-aligned s16x8 load (XT rows at stride 68 ushorts are only 8B-aligned)
__device__ inline s16x8 ld8(const unsigned short* p) {
  const s16x4 a = *(const s16x4*)(p);
  const s16x4 b = *(const s16x4*)(p + 4);
  s16x8 r;
  r[0]=a[0]; r[1]=a[1]; r[2]=a[2]; r[3]=a[3];
  r[4]=b[0]; r[5]=b[1]; r[6]=b[2]; r[7]=b[3];
  return r;
}

// LDS region A: phase-A X staging (bf16 hi/lo) -> phase-C XT staging
union RegionA {
  struct { unsigned short Hs[64][72]; unsigned short Ls[64][72]; } a;   // 18432 B
  struct { unsigned short XTh[64][68]; unsigned short XTl[64][68]; } c; // 17408 B
};
// LDS region B: G (then Cs in place) -> T hi/lo (written after Cs is dead)
union RegionB {
  float GW[64][68];                                                     // 17408 B
  struct { unsigned short Th[64][72]; unsigned short Tl[64][72]; } t;   // 18432 B
};

// One block = one batch.  Phase A: G = X X^T via bf16 hi/lo MFMA (into LDS).
// Phase B (wave 0): register LDL -> scaled coeffs Cs (in place over G) ->
// register triangular inverse -> T = diag(1/sqrt(n)) * (I+C)^{-1} to LDS.
// Phase C: out = T * X via MFMA (X re-read is L2-hot).
__global__ __launch_bounds__(256) void gs_fused_kernel(const float* __restrict__ x,
                                                       float* __restrict__ outbuf)
{
  __shared__ RegionA RA;
  __shared__ RegionB RB;
  __shared__ float ISN[64];

  const int b = blockIdx.x;
  const int t = threadIdx.x;
  const int lane = t & 63;
  const int w = t >> 6;

  const float* __restrict__ X = x + (size_t)b * SLOT;

  const int lrow = t >> 4;               // 0..15 staging row base
  const int lcol = (t & 15) * 4;         // staging col (elements)
  const int frow = lane & 15;            // MFMA frag row
  const int fk   = (lane >> 4) * 8;      // MFMA frag k offset

  // ---------------- Phase A: G = X X^T ----------------
  f32x4 acc[4];
#pragma unroll
  for (int j = 0; j < 4; ++j) { acc[j][0] = 0.f; acc[j][1] = 0.f; acc[j][2] = 0.f; acc[j][3] = 0.f; }

  for (int ch = 0; ch < 8; ++ch) {
    __syncthreads();                     // protect Hs/Ls reuse
#pragma unroll
    for (int p = 0; p < 4; ++p) {
      const int r = lrow + 16 * p;
      const f32x4 v = *(const f32x4*)(X + (size_t)r * NCOL + ch * 64 + lcol);
      u16x4 hv, lv;
#pragma unroll
      for (int j = 0; j < 4; ++j) {
        const unsigned short h = bf16h(v[j]);
        hv[j] = h;
        lv[j] = bf16h(v[j] - bf16f(h));
      }
      *(u16x4*)&RA.a.Hs[r][lcol] = hv;
      *(u16x4*)&RA.a.Ls[r][lcol] = lv;
    }
    __syncthreads();
#pragma unroll
    for (int s = 0; s < 2; ++s) {
      const int kc = s * 32 + fk;
      const s16x8 ha = *(const s16x8*)&RA.a.Hs[16 * w + frow][kc];
      const s16x8 la = *(const s16x8*)&RA.a.Ls[16 * w + frow][kc];
#pragma unroll
      for (int bt = 0; bt < 4; ++bt) {
        const s16x8 hb = *(const s16x8*)&RA.a.Hs[16 * bt + frow][kc];
        const s16x8 lb = *(const s16x8*)&RA.a.Ls[16 * bt + frow][kc];
        acc[bt] = __builtin_amdgcn_mfma_f32_16x16x32_bf16(ha, hb, acc[bt], 0, 0, 0);
        acc[bt] = __builtin_amdgcn_mfma_f32_16x16x32_bf16(ha, lb, acc[bt], 0, 0, 0);
        acc[bt] = __builtin_amdgcn_mfma_f32_16x16x32_bf16(la, hb, acc[bt], 0, 0, 0);
      }
    }
  }

  // C/D layout: col = lane&15, row = (lane>>4)*4 + reg
  {
    const int drow = (lane >> 4) * 4;
    const int dcol = lane & 15;
#pragma unroll
    for (int bt = 0; bt < 4; ++bt)
#pragma unroll
      for (int rr = 0; rr < 4; ++rr)
        RB.GW[16 * w + drow + rr][16 * bt + dcol] = acc[bt][rr];
  }
  __syncthreads();

  // ---------------- Phase B: wave-0 solve ----------------
  if (t < 64) {
    const int j = t;                     // lane = row (LDL) / column (TI)

    // W-row j of G into registers
    float wr[64];
#pragma unroll
    for (int c = 0; c < 16; ++c) {
      const f32x4 v = *(const f32x4*)&RB.GW[j][4 * c];
      wr[4 * c + 0] = v[0]; wr[4 * c + 1] = v[1]; wr[4 * c + 2] = v[2]; wr[4 * c + 3] = v[3];
    }

    // LDL: W[j][k] -= sum_{m<k} Cs[k][m]*W[j][m]; Cs[j][k] = W[j][k]/n_k.
    // Cs rebuilt in place over GW (col k written at step k; wr already loaded).
    {
      const float nk = __shfl(wr[0], 0);
      const float inv = 1.0f / nk;
      RB.GW[j][0] = wr[0] * inv;
      if (j == 0) ISN[0] = sqrtf(inv);
    }
#pragma unroll
    for (int k = 1; k < 64; ++k) {
      float a0 = 0.f, a1 = 0.f, a2 = 0.f, a3 = 0.f;
      const int K4 = k >> 2;
#pragma unroll
      for (int m4 = 0; m4 < K4; ++m4) {
        const f32x4 c4 = *(const f32x4*)&RB.GW[k][4 * m4];   // uniform broadcast
        a0 += c4[0] * wr[4 * m4 + 0];
        a1 += c4[1] * wr[4 * m4 + 1];
        a2 += c4[2] * wr[4 * m4 + 2];
        a3 += c4[3] * wr[4 * m4 + 3];
      }
#pragma unroll
      for (int m = 4 * K4; m < k; ++m) a0 += RB.GW[k][m] * wr[m];
      wr[k] -= (a0 + a1) + (a2 + a3);
      const float nk = __shfl(wr[k], k);
      const float inv = 1.0f / nk;
      RB.GW[j][k] = wr[k] * inv;
      if (j == 0) ISN[k] = sqrtf(inv);
    }

    // TI: lane j owns column j in registers; ti[i] = d(i,j) - sum Cs[i][m]*ti[m]
    float ti[64];
    ti[0] = (j == 0) ? 1.0f : 0.0f;
#pragma unroll
    for (int i = 1; i < 64; ++i) {
      float a0 = 0.f, a1 = 0.f, a2 = 0.f, a3 = 0.f;
      const int I4 = i >> 2;
#pragma unroll
      for (int m4 = 0; m4 < I4; ++m4) {
        const f32x4 c4 = *(const f32x4*)&RB.GW[i][4 * m4];   // uniform broadcast
        a0 += c4[0] * ti[4 * m4 + 0];
        a1 += c4[1] * ti[4 * m4 + 1];
        a2 += c4[2] * ti[4 * m4 + 2];
        a3 += c4[3] * ti[4 * m4 + 3];
      }
#pragma unroll
      for (int m = 4 * I4; m < i; ++m) a0 += RB.GW[i][m] * ti[m];
      ti[i] = ((i == j) ? 1.0f : 0.0f) - ((a0 + a1) + (a2 + a3));
    }

    // Emit T = diag(ISN) * TI as bf16 hi/lo (overlays GW; Cs is dead now)
#pragma unroll
    for (int i = 0; i < 64; ++i) {
      const float tf = ISN[i] * ti[i];
      const unsigned short h = bf16h(tf);
      RB.t.Th[i][j] = h;
      RB.t.Tl[i][j] = bf16h(tf - bf16f(h));
    }
  }
  __syncthreads();

  // ---------------- Phase C: out = T * X ----------------
  s16x8 tah[2], tal[2];
#pragma unroll
  for (int ks = 0; ks < 2; ++ks) {
    tah[ks] = *(const s16x8*)&RB.t.Th[16 * w + frow][ks * 32 + fk];
    tal[ks] = *(const s16x8*)&RB.t.Tl[16 * w + frow][ks * 32 + fk];
  }

  float* __restrict__ slot = outbuf + (size_t)b * SLOT;
  const int lrow4 = (t >> 4) * 4;
  const int lcol4 = (t & 15) * 4;

  for (int ch = 0; ch < 8; ++ch) {
    __syncthreads();                     // protect XT from prev-chunk readers
    float vr[4][4];
#pragma unroll
    for (int p = 0; p < 4; ++p) {
      const f32x4 v = *(const f32x4*)(X + (size_t)(lrow4 + p) * NCOL + ch * 64 + lcol4);
      vr[p][0] = v[0]; vr[p][1] = v[1]; vr[p][2] = v[2]; vr[p][3] = v[3];
    }
#pragma unroll
    for (int jj = 0; jj < 4; ++jj) {
      u16x4 hv, lv;
#pragma unroll
      for (int p = 0; p < 4; ++p) {
        const unsigned short h = bf16h(vr[p][jj]);
        hv[p] = h;
        lv[p] = bf16h(vr[p][jj] - bf16f(h));
      }
      *(u16x4*)&RA.c.XTh[lcol4 + jj][lrow4] = hv;
      *(u16x4*)&RA.c.XTl[lcol4 + jj][lrow4] = lv;
    }
    __syncthreads();

    f32x4 oacc[4];
#pragma unroll
    for (int q = 0; q < 4; ++q) { oacc[q][0] = 0.f; oacc[q][1] = 0.f; oacc[q][2] = 0.f; oacc[q][3] = 0.f; }

#pragma unroll
    for (int ks = 0; ks < 2; ++ks) {
      const int kc = ks * 32 + fk;
#pragma unroll
      for (int ct = 0; ct < 4; ++ct) {
        const s16x8 xbh = ld8(&RA.c.XTh[ct * 16 + frow][kc]);
        const s16x8 xbl = ld8(&RA.c.XTl[ct * 16 + frow][kc]);
        oacc[ct] = __builtin_amdgcn_mfma_f32_16x16x32_bf16(tah[ks], xbh, oacc[ct], 0, 0, 0);
        oacc[ct] = __builtin_amdgcn_mfma_f32_16x16x32_bf16(tah[ks], xbl, oacc[ct], 0, 0, 0);
        oacc[ct] = __builtin_amdgcn_mfma_f32_16x16x32_bf16(tal[ks], xbh, oacc[ct], 0, 0, 0);
      }
    }

    const int drow = (lane >> 4) * 4;
    const int dcol = lane & 15;
#pragma unroll
    for (int ct = 0; ct < 4; ++ct)
#pragma unroll
      for (int rr = 0; rr < 4; ++rr)
        slot[(size_t)(16 * w + drow + rr) * NCOL + ch * 64 + ct * 16 + dcol] = oacc[ct][rr];
  }
}

extern "C" void kernel_launch(void* const* d_in, const int* in_sizes, int n_in,
                              void* d_out, int out_size, void* d_ws, size_t ws_size,
                              hipStream_t stream) {
  const float* x = (const float*)d_in[0];
  float* out = (float*)d_out;
  gs_fused_kernel<<<NBATCH, 256, 0, stream>>>(x, out);
}

// Round 9
// 103.957 us; speedup vs baseline: 1.1719x; 1.1719x over previous
//
#include <hip/hip_runtime.h>
#include <hip/hip_bf16.h>
#include <cmath>

typedef __attribute__((ext_vector_type(4))) float f32x4;
typedef __attribute__((ext_vector_type(8))) short s16x8;
typedef __attribute__((ext_vector_type(4))) short s16x4;
typedef __attribute__((ext_vector_type(4))) unsigned short u16x4;

static constexpr int NCOL = 512;    // L
static constexpr int NBATCH = 1024; // 32*32
static constexpr int SLOT = 64 * NCOL;     // floats per batch slot
static constexpr int GOFF = 16384;         // G region: floats [16384, 20480)

__device__ inline unsigned short bf16h(float f) {
  return __builtin_bit_cast(unsigned short, __float2bfloat16(f));
}
__device__ inline float bf16f(unsigned short h) {
  unsigned u = ((unsigned)h) << 16;
  return __builtin_bit_cast(float, u);
}

// 8B-aligned s16x8 load (XT rows at stride 68 ushorts are only 8B-aligned)
__device__ inline s16x8 ld8(const unsigned short* p) {
  const s16x4 a = *(const s16x4*)(p);
  const s16x4 b = *(const s16x4*)(p + 4);
  s16x8 r;
  r[0]=a[0]; r[1]=a[1]; r[2]=a[2]; r[3]=a[3];
  r[4]=b[0]; r[5]=b[1]; r[6]=b[2]; r[7]=b[3];
  return r;
}

// Kernel 1: per-batch G = X X^T via bf16 hi/lo MFMA.  Lean: 18.4 KB LDS,
// no serial code -> 8 blocks/CU.  G accumulators store to the slot's G region.
__global__ __launch_bounds__(256) void gs_gram_kernel(const float* __restrict__ x,
                                                      float* __restrict__ outbuf)
{
  __shared__ unsigned short Hs[64][72];
  __shared__ unsigned short Ls[64][72];

  const int b = blockIdx.x;
  const int t = threadIdx.x;
  const int lane = t & 63;
  const int w = t >> 6;

  const float* __restrict__ X = x + (size_t)b * SLOT;

  f32x4 acc[4];
#pragma unroll
  for (int j = 0; j < 4; ++j) { acc[j][0] = 0.f; acc[j][1] = 0.f; acc[j][2] = 0.f; acc[j][3] = 0.f; }

  const int lrow = t >> 4;               // 0..15
  const int lcol = (t & 15) * 4;
  const int frow = lane & 15;
  const int fk   = (lane >> 4) * 8;

  for (int ch = 0; ch < 8; ++ch) {
    __syncthreads();
#pragma unroll
    for (int p = 0; p < 4; ++p) {
      const int r = lrow + 16 * p;
      const f32x4 v = *(const f32x4*)(X + (size_t)r * NCOL + ch * 64 + lcol);
      u16x4 hv, lv;
#pragma unroll
      for (int j = 0; j < 4; ++j) {
        const unsigned short h = bf16h(v[j]);
        hv[j] = h;
        lv[j] = bf16h(v[j] - bf16f(h));
      }
      *(u16x4*)&Hs[r][lcol] = hv;
      *(u16x4*)&Ls[r][lcol] = lv;
    }
    __syncthreads();
#pragma unroll
    for (int s = 0; s < 2; ++s) {
      const int kc = s * 32 + fk;
      const s16x8 ha = *(const s16x8*)&Hs[16 * w + frow][kc];
      const s16x8 la = *(const s16x8*)&Ls[16 * w + frow][kc];
#pragma unroll
      for (int bt = 0; bt < 4; ++bt) {
        const s16x8 hb = *(const s16x8*)&Hs[16 * bt + frow][kc];
        const s16x8 lb = *(const s16x8*)&Ls[16 * bt + frow][kc];
        acc[bt] = __builtin_amdgcn_mfma_f32_16x16x32_bf16(ha, hb, acc[bt], 0, 0, 0);
        acc[bt] = __builtin_amdgcn_mfma_f32_16x16x32_bf16(ha, lb, acc[bt], 0, 0, 0);
        acc[bt] = __builtin_amdgcn_mfma_f32_16x16x32_bf16(la, hb, acc[bt], 0, 0, 0);
      }
    }
  }

  // C/D layout: col = lane&15, row = (lane>>4)*4 + reg
  float* __restrict__ Gs = outbuf + (size_t)b * SLOT + GOFF;
  const int drow = (lane >> 4) * 4;
  const int dcol = lane & 15;
#pragma unroll
  for (int bt = 0; bt < 4; ++bt)
#pragma unroll
    for (int rr = 0; rr < 4; ++rr)
      Gs[(16 * w + drow + rr) * 64 + 16 * bt + dcol] = acc[bt][rr];
}

// Kernel 2: one wave per batch.  Register LDL -> scaled coeffs Cs in LDS ->
// register triangular inverse (lane j owns column j) -> emit
// T = diag(1/sqrt(n)) * (I+C)^{-1} PLANAR row-major: Th at u16 [0,4096),
// Tl at [4096,8192) of the slot (via in-LDS transpose + coalesced copy).
__global__ __launch_bounds__(64) void gs_solve_kernel(float* __restrict__ outbuf)
{
  __shared__ float Cs[64][68];
  __shared__ float ISN[64];

  const int b = blockIdx.x;
  const int j = threadIdx.x;             // lane = row (LDL) / column (TI)
  float* __restrict__ slot = outbuf + (size_t)b * SLOT;
  const float* __restrict__ Gs = slot + GOFF;

  // W-row j of G into registers
  float wr[64];
#pragma unroll
  for (int c = 0; c < 16; ++c) {
    const f32x4 v = *(const f32x4*)(Gs + j * 64 + 4 * c);
    wr[4 * c + 0] = v[0]; wr[4 * c + 1] = v[1]; wr[4 * c + 2] = v[2]; wr[4 * c + 3] = v[3];
  }

  // LDL: W[i][k] = G[i][k] - sum_{m<k} Cs[k][m]*W[i][m], Cs[i][k]=W[i][k]/n_k
  {
    const float nk = __shfl(wr[0], 0);
    const float inv = 1.0f / nk;
    Cs[j][0] = wr[0] * inv;
    if (j == 0) ISN[0] = sqrtf(inv);
  }
#pragma unroll
  for (int k = 1; k < 64; ++k) {
    float a0 = 0.f, a1 = 0.f, a2 = 0.f, a3 = 0.f;
    const int K4 = k >> 2;
#pragma unroll
    for (int m4 = 0; m4 < K4; ++m4) {
      const f32x4 c4 = *(const f32x4*)&Cs[k][4 * m4];   // uniform broadcast
      a0 += c4[0] * wr[4 * m4 + 0];
      a1 += c4[1] * wr[4 * m4 + 1];
      a2 += c4[2] * wr[4 * m4 + 2];
      a3 += c4[3] * wr[4 * m4 + 3];
    }
#pragma unroll
    for (int m = 4 * K4; m < k; ++m) a0 += Cs[k][m] * wr[m];
    wr[k] -= (a0 + a1) + (a2 + a3);
    const float nk = __shfl(wr[k], k);
    const float inv = 1.0f / nk;
    Cs[j][k] = wr[k] * inv;
    if (j == 0) ISN[k] = sqrtf(inv);
  }

  // TI: lane j owns column j in registers.  ti[i] = d(i,j) - sum Cs[i][m]*ti[m]
  float ti[64];
  ti[0] = (j == 0) ? 1.0f : 0.0f;
#pragma unroll
  for (int i = 1; i < 64; ++i) {
    float a0 = 0.f, a1 = 0.f, a2 = 0.f, a3 = 0.f;
    const int I4 = i >> 2;
#pragma unroll
    for (int m4 = 0; m4 < I4; ++m4) {
      const f32x4 c4 = *(const f32x4*)&Cs[i][4 * m4];   // uniform broadcast
      a0 += c4[0] * ti[4 * m4 + 0];
      a1 += c4[1] * ti[4 * m4 + 1];
      a2 += c4[2] * ti[4 * m4 + 2];
      a3 += c4[3] * ti[4 * m4 + 3];
    }
#pragma unroll
    for (int m = 4 * I4; m < i; ++m) a0 += Cs[i][m] * ti[m];
    ti[i] = ((i == j) ? 1.0f : 0.0f) - ((a0 + a1) + (a2 + a3));
  }

  // transpose T into LDS (overlay over dead Cs): lane j writes column j.
  unsigned short* __restrict__ TL = (unsigned short*)&Cs[0][0]; // 2x 64x64 u16
#pragma unroll
  for (int i = 0; i < 64; ++i) {
    const float tf = ISN[i] * ti[i];
    const unsigned short h = bf16h(tf);
    TL[i * 64 + j] = h;                            // Th plane
    TL[4096 + i * 64 + j] = bf16h(tf - bf16f(h));  // Tl plane
  }
  __syncthreads();
  // coalesced 16 KB copy to the slot head
  const unsigned int* __restrict__ TL32 = (const unsigned int*)TL;
  unsigned int* __restrict__ slotT = (unsigned int*)slot;
#pragma unroll
  for (int q = 0; q < 64; ++q) slotT[j + 64 * q] = TL32[j + 64 * q];
}

// Kernel 3: out = Tf * X per batch, pure MFMA.  T fragments loaded DIRECTLY
// from global (planar layout; 4x16B per thread, L3-hot) -> no T LDS ->
// 17.4 KB LDS total -> ~6 blocks/CU.  One barrier after the T loads
// protects the T region (slot rows 0-7) from wave-0's output stores.
__global__ __launch_bounds__(256) void gs_apply_kernel(const float* __restrict__ x,
                                                       float* __restrict__ outbuf)
{
  __shared__ unsigned short XTh[64][68];
  __shared__ unsigned short XTl[64][68];

  const int b = blockIdx.x;
  const int t = threadIdx.x;
  const int lane = t & 63;
  const int w = t >> 6;

  float* __restrict__ slot = outbuf + (size_t)b * SLOT;
  const unsigned short* __restrict__ slotU = (const unsigned short*)slot;

  const int frow = lane & 15;
  const int fk = (lane >> 4) * 8;

  // A-operand fragments straight from global: Th row 16w+frow, 8 ushorts
  s16x8 tah[2], tal[2];
#pragma unroll
  for (int ks = 0; ks < 2; ++ks) {
    tah[ks] = *(const s16x8*)&slotU[(16 * w + frow) * 64 + ks * 32 + fk];
    tal[ks] = *(const s16x8*)&slotU[4096 + (16 * w + frow) * 64 + ks * 32 + fk];
  }
  __syncthreads();   // vmcnt(0) drained at barrier: all T loads landed before any store

  const float* __restrict__ X = x + (size_t)b * SLOT;
  const int lrow4 = (t >> 4) * 4;
  const int lcol4 = (t & 15) * 4;

  for (int ch = 0; ch < 8; ++ch) {
    if (ch) __syncthreads();             // protect XT from prev-chunk readers
    float vr[4][4];
#pragma unroll
    for (int p = 0; p < 4; ++p) {
      const f32x4 v = *(const f32x4*)(X + (size_t)(lrow4 + p) * NCOL + ch * 64 + lcol4);
      vr[p][0] = v[0]; vr[p][1] = v[1]; vr[p][2] = v[2]; vr[p][3] = v[3];
    }
#pragma unroll
    for (int jj = 0; jj < 4; ++jj) {
      u16x4 hv, lv;
#pragma unroll
      for (int p = 0; p < 4; ++p) {
        const unsigned short h = bf16h(vr[p][jj]);
        hv[p] = h;
        lv[p] = bf16h(vr[p][jj] - bf16f(h));
      }
      *(u16x4*)&XTh[lcol4 + jj][lrow4] = hv;
      *(u16x4*)&XTl[lcol4 + jj][lrow4] = lv;
    }
    __syncthreads();

    f32x4 oacc[4];
#pragma unroll
    for (int q = 0; q < 4; ++q) { oacc[q][0] = 0.f; oacc[q][1] = 0.f; oacc[q][2] = 0.f; oacc[q][3] = 0.f; }

#pragma unroll
    for (int ks = 0; ks < 2; ++ks) {
      const int kc = ks * 32 + fk;
#pragma unroll
      for (int ct = 0; ct < 4; ++ct) {
        const s16x8 xbh = ld8(&XTh[ct * 16 + frow][kc]);
        const s16x8 xbl = ld8(&XTl[ct * 16 + frow][kc]);
        oacc[ct] = __builtin_amdgcn_mfma_f32_16x16x32_bf16(tah[ks], xbh, oacc[ct], 0, 0, 0);
        oacc[ct] = __builtin_amdgcn_mfma_f32_16x16x32_bf16(tah[ks], xbl, oacc[ct], 0, 0, 0);
        oacc[ct] = __builtin_amdgcn_mfma_f32_16x16x32_bf16(tal[ks], xbh, oacc[ct], 0, 0, 0);
      }
    }

    const int drow = (lane >> 4) * 4;
    const int dcol = lane & 15;
#pragma unroll
    for (int ct = 0; ct < 4; ++ct)
#pragma unroll
      for (int rr = 0; rr < 4; ++rr)
        slot[(size_t)(16 * w + drow + rr) * NCOL + ch * 64 + ct * 16 + dcol] = oacc[ct][rr];
  }
}

extern "C" void kernel_launch(void* const* d_in, const int* in_sizes, int n_in,
                              void* d_out, int out_size, void* d_ws, size_t ws_size,
                              hipStream_t stream) {
  const float* x = (const float*)d_in[0];
  float* out = (float*)d_out;
  gs_gram_kernel<<<NBATCH, 256, 0, stream>>>(x, out);
  gs_solve_kernel<<<NBATCH, 64, 0, stream>>>(out);
  gs_apply_kernel<<<NBATCH, 256, 0, stream>>>(x, out);
}